// Round 7
// baseline (1717.997 us; speedup 1.0000x reference)
//
#include <hip/hip_runtime.h>
#include <stdint.h>

// FFJORD block: B=2048, D=512, H=1024, 9 RK38 steps x 4 stages, 2 Hutchinson probes.
// f32 in/out. bf16 MFMA GEMMs, f32 accumulate, fp32 RK state.
// PRNG: JAX threefry partitionable (verified R7).
// R21: RK state in registers. R19 post-mortem: fences were ~400us (fixed) but
// FETCH stayed 1.05GB => 29MB/stage L2-miss traffic is intrinsic: per-XCD
// working set (weights 3MB + z/ACC/T 1.5MB + streams) > 4MB L2, thrashes at
// LLC latency. z/ACC/T tiles never cross blocks => move to 48 VGPRs/thread
// (statically indexed), init z from x, rep/logprob emitted from registers
// (row ss via shfl+div0 atomics + extra slab bar). Removes ~20MB/stage of
// L2-miss traffic + 48 scattered f32 loads per epilogue; weights become
// L2-resident. Also f3 K-step 64 (16 iters, 4 loads/wave, vmcnt(8)) halves
// f3 barrier count. Else identical to R19 (fence-free slab barriers, sc0).

#define B_N 2048
#define D_N 512
#define H_N 1024
#define BD (B_N * D_N)

typedef unsigned short u16;
typedef __attribute__((ext_vector_type(8))) short s16x8;   // 8 x bf16
typedef __attribute__((ext_vector_type(4))) float f32x4;   // MFMA accumulator

typedef __attribute__((address_space(1))) const uint32_t ga_u32;
typedef __attribute__((address_space(3))) uint32_t ls_u32;

#if __has_builtin(__builtin_amdgcn_alignbit)
#define ROTL32(x, r) __builtin_amdgcn_alignbit((x), (x), 32 - (r))
#else
#define ROTL32(x, r) (((x) << (r)) | ((x) >> (32 - (r))))
#endif

__device__ __forceinline__ u16 f2bf(float f) {
  union { float f; uint32_t u; } c; c.f = f;
  uint32_t r = c.u + 0x7FFFu + ((c.u >> 16) & 1u);  // RTNE
  return (u16)(r >> 16);
}
__device__ __forceinline__ float fast_tanh(float v) {
  float e = __expf(2.0f * fabsf(v));
  float t = 1.0f - 2.0f / (e + 1.0f);
  return copysignf(t, v);
}

struct U2 { uint32_t x, y; };

// Threefry-2x32, 20 rounds — KAT-verified.
__device__ __forceinline__ U2 tf2x32(uint32_t k0, uint32_t k1, uint32_t x0, uint32_t x1) {
  uint32_t k2 = k0 ^ k1 ^ 0x1BD11BDAu;
#define RND(r) { x0 += x1; x1 = ROTL32(x1, r); x1 ^= x0; }
  x0 += k0; x1 += k1;
  RND(13) RND(15) RND(26) RND(6)
  x0 += k1; x1 += k2 + 1u;
  RND(17) RND(29) RND(16) RND(24)
  x0 += k2; x1 += k0 + 2u;
  RND(13) RND(15) RND(26) RND(6)
  x0 += k0; x1 += k1 + 3u;
  RND(17) RND(29) RND(16) RND(24)
  x0 += k1; x1 += k2 + 4u;
  RND(13) RND(15) RND(26) RND(6)
  x0 += k2; x1 += k0 + 5u;
#undef RND
  U2 r; r.x = x0; r.y = x1; return r;
}

// Partitionable key schedule (verified R7).
__global__ void k_keysched(uint32_t* __restrict__ ekeys) {
  if (threadIdx.x != 0 || blockIdx.x != 0) return;
  uint32_t kx = 0u, ky = 1234u;
  for (int s = 0; s < 9; ++s) {
    for (int st = 0; st < 4; ++st) {
      U2 kst = tf2x32(kx, ky, 0u, (uint32_t)(st + 1));
      for (int pr = 0; pr < 2; ++pr) {
        U2 fo = tf2x32(kst.x, kst.y, 0u, (uint32_t)pr);
        U2 k2 = tf2x32(fo.x, fo.y, 0u, 1u);
        ekeys[(s * 4 + st) * 4 + pr * 2 + 0] = k2.x;
        ekeys[(s * 4 + st) * 4 + pr * 2 + 1] = k2.y;
      }
    }
    U2 c = tf2x32(kx, ky, 0u, 0u);
    kx = c.x; ky = c.y;
  }
}

__global__ void k_init(const float* __restrict__ x, u16* __restrict__ zin,
                       float* __restrict__ lp, float* __restrict__ d0, float* __restrict__ d1,
                       uint32_t* __restrict__ barv) {
  int i = blockIdx.x * 256 + threadIdx.x;
  if (i < BD) zin[i] = f2bf(x[i]);
  if (i < B_N) { lp[i] = 0.f; d0[i] = 0.f; d1[i] = 0.f; }
  if (i < 1024) barv[i] = 0u;                    // 32 slab counters, 128B stride
}

__global__ void k_cvtT(const float* __restrict__ src, u16* __restrict__ dst, int R, int C) {
  int i = blockIdx.x * 256 + threadIdx.x;
  if (i >= R * C) return;
  int c = i / R, r = i - c * R;
  dst[i] = f2bf(src[(size_t)r * C + c]);
}
__global__ void k_cvt(const float* __restrict__ src, u16* __restrict__ dst, int n) {
  int i = blockIdx.x * 256 + threadIdx.x;
  if (i < n) dst[i] = f2bf(src[i]);
}

__global__ void k_sentinel(float* __restrict__ out, int n) {
  int i = blockIdx.x * 256 + threadIdx.x;
  if (i < n) out[i] = 12345.0f;
}

// 8-way slab barrier, fence-free (monotonic counter, re-zeroed each replay).
// All 8 participants share one XCD L2 (the coherence point): L1 is
// write-through so stores reach L2 at vmcnt retirement; consumers bypass
// stale L1 via sc0 loads / L2 atomics. No buffer_wbl2 / buffer_inv.
__device__ __forceinline__ void slab_bar(uint32_t* ctr, uint32_t tgt) {
  asm volatile("s_waitcnt vmcnt(0)" ::: "memory");
  __syncthreads();
  if (threadIdx.x == 0) {
    __hip_atomic_fetch_add(ctr, 1u, __ATOMIC_RELAXED, __HIP_MEMORY_SCOPE_AGENT);
    while (__hip_atomic_load(ctr, __ATOMIC_RELAXED, __HIP_MEMORY_SCOPE_AGENT) < tgt)
      __builtin_amdgcn_s_sleep(1);
  }
  __syncthreads();
}

// LDS chunk swizzle (R13-verified): chunk c of 16-row-group row r at chunk c^((r>>1)&3).
// f1: 64x128 block tile, 4 waves of 32x64, K=512, 16 K-steps, 4-ring vmcnt(14).
// f3: 64x64 block tile, 4 waves of 32x32, K=1024, 16 K64-steps, 4-ring vmcnt(8).
__global__ __launch_bounds__(256, 1)
void k_fused(const uint32_t* __restrict__ keys, u16* __restrict__ ebf,
             const float* __restrict__ x, u16* __restrict__ zin,
             const u16* __restrict__ W1T, const u16* __restrict__ W2b, const u16* __restrict__ W2T,
             const float* __restrict__ b1v, const float* __restrict__ tw1v, const float* __restrict__ b2v,
             u16* __restrict__ hbuf,
             float* __restrict__ lp, float* __restrict__ div0, float* __restrict__ div1,
             uint32_t* __restrict__ barv, float* __restrict__ outp) {
  __shared__ u16 S[4][14336];   // 112KB: f1 ring [zin|e0|e1|W1|W2]x4; f3 ring (4x8192) aliased
  const int tid = threadIdx.x, wave = tid >> 6, lane = tid & 63;
  const int xcd = blockIdx.x & 7, idx = blockIdx.x >> 3;   // 256 blocks: 32/XCD
  const int bm = xcd * 4 + (idx >> 3);       // row-slab of 64, pinned to XCD
  const int bh = idx & 7;                    // f1: col-block of 128; f3: col-block of 64
  const int row0 = bm * 64;
  const int wm = wave >> 1, wn = wave & 1, r16 = lane & 15, q = lane >> 4;
  const int srow = lane >> 2;
  const int scol = (((lane & 3) ^ ((srow >> 1) & 3))) * 8;   // swizzled source chunk
  const int cqa = (q ^ ((r16 >> 1) & 3)) * 8;                // swizzled read chunk

  uint32_t* ctr = barv + bm * 32;            // this slab's barrier counter
  uint32_t tgt = 0;

  // RK state tile (64x64 per block), resident in registers for all 36 stages.
  // Element [i][j][rr] <-> row row0+wm*32+i*16+q*4+rr, col bh*64+wn*32+j*16+r16.
  float zr_[2][2][4], ac_[2][2][4], tt_[2][2][4];
#pragma unroll
  for (int i = 0; i < 2; ++i)
#pragma unroll
    for (int j = 0; j < 2; ++j)
#pragma unroll
      for (int rr = 0; rr < 4; ++rr) {
        const size_t idx2 = (size_t)(row0 + wm * 32 + i * 16 + q * 4 + rr) * D_N
                          + bh * 64 + wn * 32 + j * 16 + r16;
        zr_[i][j][rr] = x[idx2];
        ac_[i][j][rr] = 0.f; tt_[i][j][rr] = 0.f;
      }

  // ---- egen: one (stage, unit) task per call; slab-local ----
  auto egen_unit = [&](int stg, int u) {
    const int probe = u >> 10, unit = u & 1023;
    const uint32_t p0 = (uint32_t)(bm * 32768 + unit * 32);
    uint32_t k0 = keys[stg * 4 + probe * 2], k1 = keys[stg * 4 + probe * 2 + 1];
    uint4* dst = (uint4*)(ebf + (size_t)(stg & 3) * (2 * (size_t)BD) + (size_t)probe * BD + (size_t)p0);
#pragma unroll
    for (int g = 0; g < 4; ++g) {
      uint32_t pr[4];
#pragma unroll
      for (int h = 0; h < 4; ++h) {
        uint32_t c0 = p0 + g * 8 + h * 2;
        U2 r0 = tf2x32(k0, k1, 0u, c0);
        U2 r1 = tf2x32(k0, k1, 0u, c0 + 1u);
        pr[h] = (((r0.x ^ r0.y) & 1u) ? 0x3F80u : 0xBF80u) |
                (((r1.x ^ r1.y) & 1u) ? 0x3F800000u : 0xBF800000u);
      }
      uint4 v; v.x = pr[0]; v.y = pr[1]; v.z = pr[2]; v.w = pr[3];
      dst[g] = v;
    }
  };

  // Prologue: e for stages 0..3 of this slab (2048 threads x 4 tasks).
#pragma unroll
  for (int r = 0; r < 4; ++r) egen_unit(r, bh * 256 + tid);
  tgt += 8; slab_bar(ctr, tgt);

  for (int st = 0; st < 36; ++st) {
    const int s9 = st >> 2, rsub = st & 3;
    const float t0f = (float)s9 / 9.0f;
    const float t1f = (float)(s9 + 1) / 9.0f;
    const float dtt = t1f - t0f;
    const float tstage = (rsub == 0) ? t0f : (rsub == 1) ? (t0f + dtt / 3.0f)
                       : (rsub == 2) ? (t0f + dtt * 2.0f / 3.0f) : t1f;
    const float wdt = dtt * 0.125f * ((rsub == 1 || rsub == 2) ? 3.0f : 1.0f);

    // ================= f1 phase =================
    {
      const u16* e0g = ebf + (size_t)(st & 3) * (2 * (size_t)BD);
      const u16* e1g = e0g + BD;
      const int col0 = bh * 128;

      f32x4 az[2][4], au0[2][4], au1[2][4], av0[2][4], av1[2][4];
#pragma unroll
      for (int i = 0; i < 2; ++i)
#pragma unroll
        for (int j = 0; j < 4; ++j) {
          az[i][j] = (f32x4){0,0,0,0}; au0[i][j] = (f32x4){0,0,0,0}; au1[i][j] = (f32x4){0,0,0,0};
          av0[i][j] = (f32x4){0,0,0,0}; av1[i][j] = (f32x4){0,0,0,0};
        }

      // slot s = li*4+wave: s<12 -> A {zin,e0,e1} part s&3; s>=12 -> B {W1T,W2b} part (s-12)&7
      const u16* gp[7];
#pragma unroll
      for (int li = 0; li < 7; ++li) {
        const int s = li * 4 + wave;
        const u16* base;
        int row;
        if (s < 12) {
          const int mat = s >> 2;
          base = (mat == 0) ? zin : (mat == 1) ? e0g : e1g;
          row = row0 + (s & 3) * 16 + srow;
        } else {
          const int t = s - 12;
          base = (t < 8) ? W1T : W2b;
          row = col0 + (t & 7) * 16 + srow;
        }
        gp[li] = base + (size_t)row * 512 + scol;
      }

      auto stg1 = [&](int kt, int slot) {
        u16* b = &S[slot][0];
#pragma unroll
        for (int li = 0; li < 7; ++li)
          __builtin_amdgcn_global_load_lds((ga_u32*)(gp[li] + kt),
                                           (ls_u32*)(b + (li * 4 + wave) * 512), 16, 0, 1); // sc0
      };
      auto cmp1 = [&](int slot) {
        const u16* b = &S[slot][0];
        s16x8 zf[2], e0f[2], e1f[2], w1f[4], w2f[4];
#pragma unroll
        for (int i = 0; i < 2; ++i) {
          const int ao = (wm * 32 + i * 16 + r16) * 32 + cqa;
          zf[i]  = *(const s16x8*)(b + 0    + ao);
          e0f[i] = *(const s16x8*)(b + 2048 + ao);
          e1f[i] = *(const s16x8*)(b + 4096 + ao);
        }
#pragma unroll
        for (int j = 0; j < 4; ++j) {
          const int bo = (wn * 64 + j * 16 + r16) * 32 + cqa;
          w1f[j] = *(const s16x8*)(b + 6144  + bo);
          w2f[j] = *(const s16x8*)(b + 10240 + bo);
        }
#pragma unroll
        for (int i = 0; i < 2; ++i)
#pragma unroll
          for (int j = 0; j < 4; ++j) {
            az[i][j]  = __builtin_amdgcn_mfma_f32_16x16x32_bf16(zf[i],  w1f[j], az[i][j],  0, 0, 0);
            au0[i][j] = __builtin_amdgcn_mfma_f32_16x16x32_bf16(e0f[i], w1f[j], au0[i][j], 0, 0, 0);
            au1[i][j] = __builtin_amdgcn_mfma_f32_16x16x32_bf16(e1f[i], w1f[j], au1[i][j], 0, 0, 0);
            av0[i][j] = __builtin_amdgcn_mfma_f32_16x16x32_bf16(e0f[i], w2f[j], av0[i][j], 0, 0, 0);
            av1[i][j] = __builtin_amdgcn_mfma_f32_16x16x32_bf16(e1f[i], w2f[j], av1[i][j], 0, 0, 0);
          }
      };

      // 4-slot ring, 3 ahead: 21 outstanding/wave; vmcnt(14) completes oldest 7.
      stg1(0, 0); stg1(32, 1); stg1(64, 2);
      for (int it = 0; it < 16; ++it) {
        if (it < 14)        asm volatile("s_waitcnt vmcnt(14)" ::: "memory");
        else if (it == 14)  asm volatile("s_waitcnt vmcnt(7)" ::: "memory");
        else                asm volatile("s_waitcnt vmcnt(0)" ::: "memory");
        __builtin_amdgcn_s_barrier();
        if (it + 3 < 16) stg1((it + 3) * 32, (it + 3) & 3);
        cmp1(it & 3);
      }

      float d0s[2][4], d1s[2][4];
#pragma unroll
      for (int i = 0; i < 2; ++i)
#pragma unroll
        for (int rr = 0; rr < 4; ++rr) { d0s[i][rr] = 0.f; d1s[i][rr] = 0.f; }

#pragma unroll
      for (int j = 0; j < 4; ++j) {
        const int gcol = col0 + wn * 64 + j * 16 + r16;
        const float colb = b1v[gcol] + tstage * tw1v[gcol];
#pragma unroll
        for (int i = 0; i < 2; ++i) {
          const int rbase = row0 + wm * 32 + i * 16 + q * 4;   // C/D: row=quad*4+reg
#pragma unroll
          for (int rr = 0; rr < 4; ++rr) {
            float hv = fast_tanh(az[i][j][rr] + colb);
            hbuf[(size_t)(rbase + rr) * H_N + gcol] = f2bf(hv);
            float sd = 1.f - hv * hv;
            d0s[i][rr] += sd * au0[i][j][rr] * av0[i][j][rr];
            d1s[i][rr] += sd * au1[i][j][rr] * av1[i][j][rr];
          }
        }
      }
#pragma unroll
      for (int i = 0; i < 2; ++i)
#pragma unroll
        for (int rr = 0; rr < 4; ++rr) {
          float a = d0s[i][rr], bb = d1s[i][rr];
#pragma unroll
          for (int m = 1; m < 16; m <<= 1) { a += __shfl_xor(a, m); bb += __shfl_xor(bb, m); }
          if (r16 == 0) {
            int grow = row0 + wm * 32 + i * 16 + q * 4 + rr;
            atomicAdd(&div0[grow], a);
            atomicAdd(&div1[grow], bb);
          }
        }
    }
    tgt += 8; slab_bar(ctr, tgt);

    // ================= f3 phase (+ lp/div apply, + egen for stage st+4) =================
    {
      const int col0 = bh * 64;
      u16* S3 = &S[0][0];      // 4 ring slots of 8192 u16: [A k0 2048|A k1 2048|B k0 2048|B k1 2048]

      f32x4 a3[2][2];
      a3[0][0] = (f32x4){0,0,0,0}; a3[0][1] = (f32x4){0,0,0,0};
      a3[1][0] = (f32x4){0,0,0,0}; a3[1][1] = (f32x4){0,0,0,0};

      const u16* gp3a = hbuf + (size_t)(row0 + wave * 16 + srow) * 1024 + scol;
      const u16* gp3b = W2T  + (size_t)(col0 + wave * 16 + srow) * 1024 + scol;

      // K-step 64: 4 loads/wave/step (A k0, A k1, B k0, B k1).
      auto stg3 = [&](int kt, int slot) {
        u16* b = S3 + slot * 8192;
        __builtin_amdgcn_global_load_lds((ga_u32*)(gp3a + kt),
                                         (ls_u32*)(b + wave * 512), 16, 0, 1);            // sc0
        __builtin_amdgcn_global_load_lds((ga_u32*)(gp3a + kt + 32),
                                         (ls_u32*)(b + 2048 + wave * 512), 16, 0, 1);     // sc0
        __builtin_amdgcn_global_load_lds((ga_u32*)(gp3b + kt),
                                         (ls_u32*)(b + 4096 + wave * 512), 16, 0, 1);     // sc0
        __builtin_amdgcn_global_load_lds((ga_u32*)(gp3b + kt + 32),
                                         (ls_u32*)(b + 6144 + wave * 512), 16, 0, 1);     // sc0
      };
      auto cmp3 = [&](int slot) {
        const u16* b = S3 + slot * 8192;
#pragma unroll
        for (int ks = 0; ks < 2; ++ks) {
          s16x8 af[2], bf[2];
#pragma unroll
          for (int i = 0; i < 2; ++i)
            af[i] = *(const s16x8*)(b + ks * 2048 + (wm * 32 + i * 16 + r16) * 32 + cqa);
#pragma unroll
          for (int j = 0; j < 2; ++j)
            bf[j] = *(const s16x8*)(b + 4096 + ks * 2048 + (wn * 32 + j * 16 + r16) * 32 + cqa);
#pragma unroll
          for (int i = 0; i < 2; ++i)
#pragma unroll
            for (int j = 0; j < 2; ++j)
              a3[i][j] = __builtin_amdgcn_mfma_f32_16x16x32_bf16(af[i], bf[j], a3[i][j], 0, 0, 0);
        }
      };

      // 4-slot ring, 3 ahead: 12 outstanding/wave; vmcnt(8) completes oldest 4.
      stg3(0, 0); stg3(64, 1); stg3(128, 2);
      for (int it = 0; it < 16; ++it) {
        if (it < 14)        asm volatile("s_waitcnt vmcnt(8)" ::: "memory");
        else if (it == 14)  asm volatile("s_waitcnt vmcnt(4)" ::: "memory");
        else                asm volatile("s_waitcnt vmcnt(0)" ::: "memory");
        __builtin_amdgcn_s_barrier();
        if (it + 3 < 16) stg3((it + 3) * 64, (it + 3) & 3);
        cmp3(it & 3);
      }

      if (bh == 0 && tid < 64) {           // apply clipped div to lp; reset accumulators
        int b = row0 + tid;
        float c0 = __hip_atomic_load(&div0[b], __ATOMIC_RELAXED, __HIP_MEMORY_SCOPE_AGENT);
        float c1 = __hip_atomic_load(&div1[b], __ATOMIC_RELAXED, __HIP_MEMORY_SCOPE_AGENT);
        float c = 0.5f * (c0 + c1);
        c = fminf(fmaxf(c, -100.f), 100.f);
        lp[b] -= wdt * c;
        div0[b] = 0.f; div1[b] = 0.f;
      }

      // RK38 epilogue — register state, zin (bf16) is the only global output.
#pragma unroll
      for (int j = 0; j < 2; ++j) {
        const int gcol = col0 + wn * 32 + j * 16 + r16;
        const float cb = b2v[gcol];
#pragma unroll
        for (int i = 0; i < 2; ++i) {
          const int rbase = row0 + wm * 32 + i * 16 + q * 4;
#pragma unroll
          for (int rr = 0; rr < 4; ++rr) {
            const size_t idx2 = (size_t)(rbase + rr) * D_N + gcol;
            const float f = a3[i][j][rr] + cb;
            if (rsub == 0) {
              ac_[i][j][rr] = dtt * 0.125f * f;
              tt_[i][j][rr] = dtt * f;
              zin[idx2] = f2bf(zr_[i][j][rr] + dtt * f * (1.f / 3.f));
            } else if (rsub == 1) {
              float t_ = tt_[i][j][rr];
              ac_[i][j][rr] += 0.375f * dtt * f;
              zin[idx2] = f2bf(zr_[i][j][rr] + dtt * f - t_ * (1.f / 3.f));
              tt_[i][j][rr] = t_ - dtt * f;
            } else if (rsub == 2) {
              ac_[i][j][rr] += 0.375f * dtt * f;
              zin[idx2] = f2bf(zr_[i][j][rr] + tt_[i][j][rr] + dtt * f);
            } else {
              float zn = zr_[i][j][rr] + ac_[i][j][rr] + dtt * 0.125f * f;
              zr_[i][j][rr] = zn;
              zin[idx2] = f2bf(zn);
            }
          }
        }
      }

      // regen e for stage st+4 into the slot f1(st) just freed (slab-local).
      if (st + 4 < 36) egen_unit(st + 4, bh * 256 + tid);
    }
    tgt += 8; slab_bar(ctr, tgt);
  }

  // ================= out phase: rep from registers + logprob =================
  // rep write + per-row partial ss -> div0 (zeroed at st=35) via atomics.
#pragma unroll
  for (int i = 0; i < 2; ++i) {
#pragma unroll
    for (int rr = 0; rr < 4; ++rr) {
      const int grow = row0 + wm * 32 + i * 16 + q * 4 + rr;
      float val = 0.f;
#pragma unroll
      for (int j = 0; j < 2; ++j) {
        const int gcol = bh * 64 + wn * 32 + j * 16 + r16;
        const float v = zr_[i][j][rr];
        outp[(size_t)grow * D_N + gcol] = v;
        val += v * v;
      }
#pragma unroll
      for (int m = 1; m < 16; m <<= 1) val += __shfl_xor(val, m);
      if (r16 == 0) atomicAdd(&div0[grow], val);
    }
  }
  tgt += 8; slab_bar(ctr, tgt);
  if (bh == 0 && tid < 64) {
    const int b = row0 + tid;
    float ss = __hip_atomic_load(&div0[b], __ATOMIC_RELAXED, __HIP_MEMORY_SCOPE_AGENT);
    float lpv = __hip_atomic_load(&lp[b], __ATOMIC_RELAXED, __HIP_MEMORY_SCOPE_AGENT);
    outp[(size_t)BD + b] = -0.5f * ss + lpv;
  }
}

extern "C" void kernel_launch(void* const* d_in, const int* in_sizes, int n_in,
                              void* d_out, int out_size, void* d_ws, size_t ws_size,
                              hipStream_t stream) {
  const float* x   = (const float*)d_in[0];
  const float* W1  = (const float*)d_in[1];
  const float* b1  = (const float*)d_in[2];
  const float* tw1 = (const float*)d_in[3];
  const float* W2  = (const float*)d_in[4];
  const float* b2  = (const float*)d_in[5];
  float* outp = (float*)d_out;

  const size_t NEEDED = (size_t)45 << 20;
  if (ws_size < NEEDED) {
    k_sentinel<<<(BD + B_N + 255) / 256, 256, 0, stream>>>(outp, BD + B_N);
    return;
  }
  char* w = (char*)d_ws;
  auto carve = [&](size_t bytes) { char* p = w; w += (bytes + 255) & ~(size_t)255; return p; };
  uint32_t* keys = (uint32_t*)carve(144 * sizeof(uint32_t));
  u16* ebf   = (u16*)carve((size_t)4 * 2 * BD * 2);               // 16 MB: 4-slot e ring
  u16* zin   = (u16*)carve((size_t)BD * 2);
  u16* hbuf  = (u16*)carve((size_t)B_N * H_N * 2);
  u16* W1T   = (u16*)carve((size_t)H_N * D_N * 2);
  u16* W2b   = (u16*)carve((size_t)H_N * D_N * 2);
  u16* W2T   = (u16*)carve((size_t)D_N * H_N * 2);
  float* lp   = (float*)carve((size_t)B_N * 4);
  float* div0 = (float*)carve((size_t)B_N * 4);
  float* div1 = (float*)carve((size_t)B_N * 4);
  uint32_t* barv = (uint32_t*)carve(4096);       // 32 slab counters, 128B stride

  k_keysched<<<1, 1, 0, stream>>>(keys);
  k_init<<<BD / 256, 256, 0, stream>>>(x, zin, lp, div0, div1, barv);
  k_cvtT<<<(D_N * H_N) / 256, 256, 0, stream>>>(W1, W1T, D_N, H_N);
  k_cvt <<<(H_N * D_N) / 256, 256, 0, stream>>>(W2, W2b, H_N * D_N);
  k_cvtT<<<(H_N * D_N) / 256, 256, 0, stream>>>(W2, W2T, H_N, D_N);

  k_fused<<<256, 256, 0, stream>>>(keys, ebf, x, zin, W1T, W2b, W2T, b1, tw1, b2,
                                   hbuf, lp, div0, div1, barv, outp);
}